// Round 5
// baseline (438.219 us; speedup 1.0000x reference)
//
#include <hip/hip_runtime.h>
#include <math.h>

static constexpr int N_NODES = 50000;
static constexpr int N_EDGES = 800000;
static constexpr int DMODEL  = 128;
static constexpr int MTILES  = N_NODES / 16;   // 3125 exactly
static constexpr int CAPLOG  = 6;              // 64 slots/node; max degree ~40 (Poisson(16))
static constexpr int ESPLIT  = 400384;         // 391 blocks * 1024 edges

typedef __attribute__((ext_vector_type(8))) short short8;   // 8 bf16 (4 VGPRs)
typedef __attribute__((ext_vector_type(4))) float float4v;  // 4 fp32 acc

__device__ __forceinline__ unsigned short f2bf(float f) {
    unsigned u = __builtin_bit_cast(unsigned, f);
    u += 0x7fffu + ((u >> 16) & 1u);
    return (unsigned short)(u >> 16);
}
__device__ __forceinline__ float bf2f(unsigned short b) {
    unsigned u = ((unsigned)b) << 16;
    return __builtin_bit_cast(float, u);
}

// ---------------------------------------------------------------------------
// Weight prep: fp32 [K][N] row-major -> bf16 MFMA B-fragment order.
//   idx = (nt*ksteps + s)*512 + quad*128 + c*8 + j   (nt=n>>4, c=n&15, s=k>>5)
// ---------------------------------------------------------------------------
struct PrepSeg { const float* src; int K; int N; int dstOff; };
struct PrepArgs { PrepSeg seg[13]; };

__global__ void prep_kernel(PrepArgs pa, unsigned short* wf)
{
    PrepSeg sg = pa.seg[blockIdx.y];
    int e = blockIdx.x * 256 + threadIdx.x;
    int total = sg.K * sg.N;
    if (e >= total) return;
    int n = e % sg.N;
    int k = e / sg.N;
    int ks = sg.K >> 5;
    int nt = n >> 4, c = n & 15, s = k >> 5, q = (k >> 3) & 3, jj = k & 7;
    int di = sg.dstOff + (nt * ks + s) * 512 + q * 128 + c * 8 + jj;
    wf[di] = f2bf(sg.src[e]);
}

// ---------------------------------------------------------------------------
// Padded one-pass bucket build body: rank = atomicAdd(counts[dst]), slot into
// eslot[dst*64 + rank]. Fused into GEMM dispatches (extra blockIdx.y
// partition) so the atomic latency hides under MFMA/BW-bound work.
// ---------------------------------------------------------------------------
__device__ __forceinline__ void scatter_body(
    const int* __restrict__ src, const int* __restrict__ dst,
    int* counts, int* eslot, int ebeg, int eend)
{
    int base = ebeg + blockIdx.x * 1024 + threadIdx.x;
    int d[4], s[4];
    bool v[4];
#pragma unroll
    for (int k = 0; k < 4; ++k) {
        int e = base + k * 256;
        v[k] = e < eend;
        int ec = v[k] ? e : ebeg;
        d[k] = dst[ec];
        s[k] = src[ec];
    }
#pragma unroll
    for (int k = 0; k < 4; ++k) {
        if (v[k]) {
            int r = atomicAdd(&counts[d[k]], 1);
            eslot[(d[k] << CAPLOG) + r] = s[k];
        }
    }
}

// ---------------------------------------------------------------------------
// LDS-free MFMA GEMM body. Wave = 16-row m-tile x NT*16 cols; B-frags in
// VGPRs (loaded once per wave). EPI: 0=bias, 1=bias+relu, 2=bias+residual,
// 3=bias+residual+LayerNorm (requires NT*16==128, colBase==0).
// ---------------------------------------------------------------------------
template<int KSTEPS, int NT, int EPI, bool AF32, bool WRF, bool WRB>
__device__ __forceinline__ void gemm_body(
    const void* __restrict__ Ap, const unsigned short* __restrict__ Wfc,
    const float* __restrict__ bias, const float* res,
    float* Cf, unsigned short* Cb,
    const float* __restrict__ lnw, const float* __restrict__ lnb,
    int ldA, int ldC, int mtiles, int colBase)
{
    const int lane = threadIdx.x & 63;
    const int c = lane & 15;
    const int q = lane >> 4;

    short8 bfrag[NT][KSTEPS];
#pragma unroll
    for (int nt = 0; nt < NT; ++nt)
#pragma unroll
        for (int s = 0; s < KSTEPS; ++s)
            bfrag[nt][s] = *(const short8*)(Wfc + (nt * KSTEPS + s) * 512 + lane * 8);

    float bb[NT];
#pragma unroll
    for (int nt = 0; nt < NT; ++nt)
        bb[nt] = bias ? bias[colBase + nt * 16 + c] : 0.f;

    float lw[NT], lb[NT];
    if (EPI == 3) {
#pragma unroll
        for (int nt = 0; nt < NT; ++nt) {
            lw[nt] = lnw[nt * 16 + c];
            lb[nt] = lnb[nt * 16 + c];
        }
    }

    const int wid = blockIdx.x * 4 + (threadIdx.x >> 6);
    const int nw  = gridDim.x * 4;

    for (int mt = wid; mt < mtiles; mt += nw) {
        const int row0 = mt * 16;
        short8 afrag[KSTEPS];
        if (AF32) {
            const float* A32 = (const float*)Ap;
#pragma unroll
            for (int s = 0; s < KSTEPS; ++s) {
                const float4* p = (const float4*)(A32 + (size_t)(row0 + c) * ldA + s * 32 + q * 8);
                float4 x0 = p[0], x1 = p[1];
                short8 a;
                a[0] = (short)f2bf(x0.x); a[1] = (short)f2bf(x0.y);
                a[2] = (short)f2bf(x0.z); a[3] = (short)f2bf(x0.w);
                a[4] = (short)f2bf(x1.x); a[5] = (short)f2bf(x1.y);
                a[6] = (short)f2bf(x1.z); a[7] = (short)f2bf(x1.w);
                afrag[s] = a;
            }
        } else {
            const unsigned short* Ab = (const unsigned short*)Ap;
#pragma unroll
            for (int s = 0; s < KSTEPS; ++s)
                afrag[s] = *(const short8*)(Ab + (size_t)(row0 + c) * ldA + s * 32 + q * 8);
        }

        float4v acc[NT];
#pragma unroll
        for (int nt = 0; nt < NT; ++nt) acc[nt] = (float4v)0.f;
#pragma unroll
        for (int s = 0; s < KSTEPS; ++s)
#pragma unroll
            for (int nt = 0; nt < NT; ++nt)
                acc[nt] = __builtin_amdgcn_mfma_f32_16x16x32_bf16(afrag[s], bfrag[nt][s], acc[nt], 0, 0, 0);

        // epilogue: C row = row0 + q*4 + r, col = colBase + nt*16 + c
#pragma unroll
        for (int nt = 0; nt < NT; ++nt) {
            const int col = colBase + nt * 16 + c;
#pragma unroll
            for (int r = 0; r < 4; ++r) {
                const int grow = row0 + q * 4 + r;
                float v = acc[nt][r] + bb[nt];
                if (EPI == 2 || EPI == 3) v += res[(size_t)grow * ldC + col];
                if (EPI == 1) v = fmaxf(v, 0.f);
                acc[nt][r] = v;
            }
        }

        if (EPI == 3) {
            // full-row LayerNorm: reduce over 16 lanes of quad (cols) x NT regs
#pragma unroll
            for (int r = 0; r < 4; ++r) {
                float s = 0.f, ss = 0.f;
#pragma unroll
                for (int nt = 0; nt < NT; ++nt) {
                    float v = acc[nt][r];
                    s += v; ss = fmaf(v, v, ss);
                }
#pragma unroll
                for (int o = 1; o < 16; o <<= 1) {
                    s  += __shfl_xor(s, o, 64);
                    ss += __shfl_xor(ss, o, 64);
                }
                float m   = s * (1.0f / 128.0f);
                float var = ss * (1.0f / 128.0f) - m * m;
                float rs  = rsqrtf(var + 1e-5f);
                const int grow = row0 + q * 4 + r;
#pragma unroll
                for (int nt = 0; nt < NT; ++nt) {
                    float v = (acc[nt][r] - m) * rs * lw[nt] + lb[nt];
                    if (WRF) Cf[(size_t)grow * ldC + nt * 16 + c] = v;
                    if (WRB) Cb[(size_t)grow * ldC + nt * 16 + c] = f2bf(v);
                }
            }
        } else {
#pragma unroll
            for (int nt = 0; nt < NT; ++nt) {
                const int col = colBase + nt * 16 + c;
#pragma unroll
                for (int r = 0; r < 4; ++r) {
                    const int grow = row0 + q * 4 + r;
                    if (WRF) Cf[(size_t)grow * ldC + col] = acc[nt][r];
                    if (WRB) Cb[(size_t)grow * ldC + col] = f2bf(acc[nt][r]);
                }
            }
        }
    }
}

template<int KSTEPS, int NT, int EPI, bool AF32, bool WRF, bool WRB>
__global__ __launch_bounds__(256, 2)
void mfma_gemm(const void* __restrict__ Ap, const unsigned short* __restrict__ Wf,
               const float* __restrict__ bias, const float* res,
               float* Cf, unsigned short* Cb,
               const float* __restrict__ lnw, const float* __restrict__ lnb,
               int ldA, int ldC, int mtiles)
{
    const int colBase = blockIdx.y * NT * 16;
    const unsigned short* Wfc = Wf + (size_t)blockIdx.y * NT * KSTEPS * 512;
    gemm_body<KSTEPS, NT, EPI, AF32, WRF, WRB>(
        Ap, Wfc, bias, res, Cf, Cb, lnw, lnb, ldA, ldC, mtiles, colBase);
}

// Embedding GEMM fused with scatter half 1 (blockIdx.y==1 -> scatter).
__global__ __launch_bounds__(256, 2)
void emb_sc_gemm(const float* __restrict__ A, const unsigned short* __restrict__ Wf,
                 float* Cf, unsigned short* Cb, int mtiles,
                 const int* __restrict__ src, const int* __restrict__ dst,
                 int* counts, int* eslot, int ebeg, int eend)
{
    if (blockIdx.y == 1) {
        scatter_body(src, dst, counts, eslot, ebeg, eend);
        return;
    }
    gemm_body<4, 8, 0, true, true, true>(
        A, Wf, nullptr, nullptr, Cf, Cb, nullptr, nullptr, 128, 128, mtiles, 0);
}

// Q/K/V fused + scatter half 2 (blockIdx.y==3 -> scatter on layer 0).
// K and V write into the interleaved kv buffer [node][K 0..127 | V 128..255]
// via per-sel out pointer + ldC.
struct QkvPtrs { const float* bias[3]; unsigned short* out[3]; int ldc[3]; };

__global__ __launch_bounds__(256, 2)
void qkv_sc_gemm(const unsigned short* __restrict__ A, const unsigned short* __restrict__ WfBase,
                 QkvPtrs ptrs, int mtiles,
                 const int* __restrict__ src, const int* __restrict__ dst,
                 int* counts, int* eslot, int ebeg, int eend)
{
    if (blockIdx.y == 3) {
        scatter_body(src, dst, counts, eslot, ebeg, eend);
        return;
    }
    const int sel = blockIdx.y;
    gemm_body<4, 8, 0, false, false, true>(
        A, WfBase + (size_t)sel * 32768, ptrs.bias[sel], nullptr,
        nullptr, ptrs.out[sel], nullptr, nullptr, 128, ptrs.ldc[sel], mtiles, 0);
}

// ---------------------------------------------------------------------------
// LayerNorm rows of [M,128] fp32; writes fp32 (+optional bf16 mirror).
// ---------------------------------------------------------------------------
__global__ __launch_bounds__(256)
void ln_kernel(const float* x, const float* __restrict__ w,
               const float* __restrict__ b, float* outf, unsigned short* outb, int M)
{
    int row  = (int)((blockIdx.x * 256 + threadIdx.x) >> 6);
    int lane = threadIdx.x & 63;
    if (row >= M) return;
    const float* xr = x + (size_t)row * 128;
    float x0 = xr[lane];
    float x1 = xr[lane + 64];
    float s  = x0 + x1;
    float ss = x0 * x0 + x1 * x1;
#pragma unroll
    for (int o = 1; o < 64; o <<= 1) {
        s  += __shfl_xor(s, o, 64);
        ss += __shfl_xor(ss, o, 64);
    }
    float m   = s * (1.0f / 128.0f);
    float var = ss * (1.0f / 128.0f) - m * m;
    float rs  = rsqrtf(var + 1e-5f);
    float o0 = (x0 - m) * rs * w[lane] + b[lane];
    float o1 = (x1 - m) * rs * w[lane + 64] + b[lane + 64];
    outf[(size_t)row * 128 + lane]      = o0;
    outf[(size_t)row * 128 + lane + 64] = o1;
    if (outb) {
        outb[(size_t)row * 128 + lane]      = f2bf(o0);
        outb[(size_t)row * 128 + lane + 64] = f2bf(o1);
    }
}

// ---------------------------------------------------------------------------
// Attention aggregation, 16-lanes-per-edge, 8 edges/iter with:
//  (a) bucket-index preload: CAP=64 slots = 1 int/lane, ONE coalesced load;
//      per-iteration src indices come from __shfl (no dependent index loads).
//  (b) double-buffered gather prefetch: iteration t+1's 4 dwordx4 gathers are
//      issued before waiting on iteration t's (counted vmcnt) so consecutive
//      gather round-trips overlap within a wave.
//   wave = one dst node; quarter g=lane>>4 owns edge slots g and g+4; lane
//   li=lane&15 covers dims 8*li..8*li+7 (head = li>>1). K|V interleaved rows:
//   each edge reads one contiguous 512B region (K at +0, V at +128 elems).
//   Head score = 1 xor-1 shuffle. Final cross-quarter combine: xor-16/32.
//   Masked slots use slot 0 (valid whenever deg>0); deg==0 guarded.
//   attn may alias q (row w read at start / written at end by wave w only).
// ---------------------------------------------------------------------------
__global__ __launch_bounds__(256)
void agg_kernel(const unsigned short* qv, const unsigned short* __restrict__ kvv,
                const int* __restrict__ counts, const int* __restrict__ eslot,
                unsigned short* attn, int n_nodes)
{
    int w    = (int)((blockIdx.x * 256 + threadIdx.x) >> 6);
    int lane = threadIdx.x & 63;
    if (w >= n_nodes) return;
    const int g  = lane >> 4;   // edge slot within iteration
    const int li = lane & 15;   // 8-dim chunk; head = li>>1

    // whole bucket's indices: lane l holds eslot[w*64 + l] (one 256B load/wave)
    int ebuf = eslot[(w << CAPLOG) + lane];
    int deg  = counts[w];

    // q chunk: dims 8*li .. 8*li+7 (quarters redundantly load same 256B row -> L1)
    float qf[8];
    {
        uint4 qb = *(const uint4*)(qv + (size_t)w * 128 + li * 8);
        const unsigned* qp = (const unsigned*)&qb;
#pragma unroll
        for (int j = 0; j < 4; ++j) {
            qf[2 * j]     = bf2f((unsigned short)(qp[j] & 0xffff));
            qf[2 * j + 1] = bf2f((unsigned short)(qp[j] >> 16));
        }
    }

    float acc[8] = {0.f, 0.f, 0.f, 0.f, 0.f, 0.f, 0.f, 0.f};
    float z = 0.f;

    if (deg > 0) {
        // ---- initial gather (iteration 0) ----
        int  i0 = g, i1 = g + 4;
        bool cv0 = i0 < deg, cv1 = i1 < deg;
        int  s0 = __shfl(ebuf, cv0 ? i0 : 0, 64);
        int  s1 = __shfl(ebuf, cv1 ? i1 : 0, 64);
        const unsigned short* a0 = kvv + (size_t)s0 * 256 + li * 8;
        const unsigned short* a1 = kvv + (size_t)s1 * 256 + li * 8;
        uint4 kA0 = *(const uint4*)(a0);
        uint4 vA0 = *(const uint4*)(a0 + 128);
        uint4 kA1 = *(const uint4*)(a1);
        uint4 vA1 = *(const uint4*)(a1 + 128);

        for (int base = 0; base < deg; base += 8) {
            // ---- prefetch next iteration's gathers (masked -> slot 0, L1-hot) ----
            int  n0 = base + 8 + g, n1 = base + 8 + g + 4;
            bool nv0 = n0 < deg, nv1 = n1 < deg;
            int  t0 = __shfl(ebuf, nv0 ? n0 : 0, 64);
            int  t1 = __shfl(ebuf, nv1 ? n1 : 0, 64);
            const unsigned short* b0 = kvv + (size_t)t0 * 256 + li * 8;
            const unsigned short* b1 = kvv + (size_t)t1 * 256 + li * 8;
            uint4 kB0 = *(const uint4*)(b0);
            uint4 vB0 = *(const uint4*)(b0 + 128);
            uint4 kB1 = *(const uint4*)(b1);
            uint4 vB1 = *(const uint4*)(b1 + 128);

            // ---- compute on current buffers ----
            const unsigned* kp0 = (const unsigned*)&kA0;
            const unsigned* kp1 = (const unsigned*)&kA1;
            float p0 = 0.f, p1 = 0.f;
#pragma unroll
            for (int j = 0; j < 4; ++j) {
                p0 = fmaf(bf2f((unsigned short)(kp0[j] & 0xffff)), qf[2 * j],     p0);
                p0 = fmaf(bf2f((unsigned short)(kp0[j] >> 16)),    qf[2 * j + 1], p0);
                p1 = fmaf(bf2f((unsigned short)(kp1[j] & 0xffff)), qf[2 * j],     p1);
                p1 = fmaf(bf2f((unsigned short)(kp1[j] >> 16)),    qf[2 * j + 1], p1);
            }
            p0 += __shfl_xor(p0, 1, 64);   // full 16-dim head score
            p1 += __shfl_xor(p1, 1, 64);

            float sv0 = __expf(fminf(fmaxf(p0 * 0.25f, -5.f), 5.f));
            float sv1 = __expf(fminf(fmaxf(p1 * 0.25f, -5.f), 5.f));
            sv0 = cv0 ? sv0 : 0.f;
            sv1 = cv1 ? sv1 : 0.f;

            const unsigned* vp0 = (const unsigned*)&vA0;
            const unsigned* vp1 = (const unsigned*)&vA1;
#pragma unroll
            for (int j = 0; j < 4; ++j) {
                acc[2 * j]     = fmaf(sv0, bf2f((unsigned short)(vp0[j] & 0xffff)), acc[2 * j]);
                acc[2 * j + 1] = fmaf(sv0, bf2f((unsigned short)(vp0[j] >> 16)),    acc[2 * j + 1]);
                acc[2 * j]     = fmaf(sv1, bf2f((unsigned short)(vp1[j] & 0xffff)), acc[2 * j]);
                acc[2 * j + 1] = fmaf(sv1, bf2f((unsigned short)(vp1[j] >> 16)),    acc[2 * j + 1]);
            }
            z += sv0 + sv1;

            // ---- rotate buffers / validity ----
            kA0 = kB0; vA0 = vB0; kA1 = kB1; vA1 = vB1;
            cv0 = nv0; cv1 = nv1;
        }
    }

    // combine the 4 edge-slot quarters (each lane group holds same dims/head)
#pragma unroll
    for (int o = 16; o < 64; o <<= 1) {
#pragma unroll
        for (int j = 0; j < 8; ++j) acc[j] += __shfl_xor(acc[j], o, 64);
        z += __shfl_xor(z, o, 64);
    }

    if (g == 0) {
        float inv = 1.f / (z + 1e-6f);
        unsigned ow[4];
#pragma unroll
        for (int j = 0; j < 4; ++j)
            ow[j] = (unsigned)f2bf(acc[2 * j] * inv) |
                    ((unsigned)f2bf(acc[2 * j + 1] * inv) << 16);
        *(uint4*)(attn + (size_t)w * 128 + li * 8) = *(const uint4*)ow;
    }
}

// ---------------------------------------------------------------------------
extern "C" void kernel_launch(void* const* d_in, const int* in_sizes, int n_in,
                              void* d_out, int out_size, void* d_ws, size_t ws_size,
                              hipStream_t stream)
{
    const float* h_in  = (const float*)d_in[0];
    const int*   src   = (const int*)d_in[1];
    const int*   dst   = (const int*)d_in[2];
    const float* W_emb = (const float*)d_in[3];
    const float* Wq    = (const float*)d_in[4];
    const float* bq    = (const float*)d_in[5];
    const float* Wk    = (const float*)d_in[6];
    const float* bk    = (const float*)d_in[7];
    const float* Wv    = (const float*)d_in[8];
    const float* bv    = (const float*)d_in[9];
    const float* Wo    = (const float*)d_in[10];
    const float* bo    = (const float*)d_in[11];
    const float* ln1w  = (const float*)d_in[12];
    const float* ln1b  = (const float*)d_in[13];
    const float* Wf1   = (const float*)d_in[14];
    const float* bf1   = (const float*)d_in[15];
    const float* Wf2   = (const float*)d_in[16];
    const float* bf2   = (const float*)d_in[17];
    const float* ln2w  = (const float*)d_in[18];
    const float* ln2b  = (const float*)d_in[19];
    float* out = (float*)d_out;

    const int N = N_NODES, E = N_EDGES;
    const size_t NF = (size_t)N * DMODEL;

    float*          hbuf  = (float*)d_ws;
    unsigned short* hbf   = (unsigned short*)(hbuf + NF);
    unsigned short* qbuf  = hbf + NF;
    unsigned short* kvbuf = qbuf + NF;        // [N][256]: K row | V row interleaved
    unsigned short* wf    = kvbuf + 2 * NF;
    int* counts = (int*)(wf + 278528);
    // padded edge buckets live in d_out: dead until the final ln_kernel
    // (which completely overwrites it). 50K * 64 slots * 4B = 12.8 MB < 25.6 MB.
    int* eslot  = (int*)d_out;
    unsigned short* fbuf = kvbuf;   // [N][256] bf16 FFN hidden (same footprint)

    const int EMB_O = 0, Q_O = 16384, K_O = 49152, V_O = 81920, O_O = 114688,
              F1_O = 147456, F2_O = 212992;

    const int rowBlocks = (N + 3) / 4;
    const int GX = 391;

    // ---- counts zero (scatter halves are fused into emb/qkv dispatches) ----
    hipMemsetAsync(counts, 0, (size_t)N * sizeof(int), stream);

    // ---- weight prep ----
    PrepArgs pa;
    pa.seg[0]  = {W_emb,          128, 128, EMB_O};
    pa.seg[1]  = {Wq,             128, 128, Q_O};
    pa.seg[2]  = {Wq + 16384,     128, 128, Q_O + 16384};
    pa.seg[3]  = {Wk,             128, 128, K_O};
    pa.seg[4]  = {Wk + 16384,     128, 128, K_O + 16384};
    pa.seg[5]  = {Wv,             128, 128, V_O};
    pa.seg[6]  = {Wv + 16384,     128, 128, V_O + 16384};
    pa.seg[7]  = {Wo,             128, 128, O_O};
    pa.seg[8]  = {Wo + 16384,     128, 128, O_O + 16384};
    pa.seg[9]  = {Wf1,            128, 256, F1_O};
    pa.seg[10] = {Wf1 + 32768,    128, 256, F1_O + 32768};
    pa.seg[11] = {Wf2,            256, 128, F2_O};
    pa.seg[12] = {Wf2 + 32768,    256, 128, F2_O + 32768};
    prep_kernel<<<dim3(128, 13), 256, 0, stream>>>(pa, wf);

    // ---- embedding GEMM + scatter half 1 (edges [0, ESPLIT)) ----
    emb_sc_gemm<<<dim3(GX, 2), 256, 0, stream>>>(
        h_in, wf + EMB_O, hbuf, hbf, MTILES, src, dst, counts, eslot, 0, ESPLIT);

    for (int l = 0; l < 2; ++l) {
        // Q,K,V in one dispatch (+ scatter half 2 on layer 0)
        QkvPtrs qp;
        qp.bias[0] = bq + l * 128; qp.bias[1] = bk + l * 128; qp.bias[2] = bv + l * 128;
        qp.out[0] = qbuf;   qp.ldc[0] = 128;
        qp.out[1] = kvbuf;  qp.ldc[1] = 256;
        qp.out[2] = kvbuf + 128; qp.ldc[2] = 256;
        qkv_sc_gemm<<<dim3(GX, l == 0 ? 4 : 3), 256, 0, stream>>>(
            hbf, wf + Q_O + l * 16384, qp, MTILES, src, dst, counts, eslot, ESPLIT, E);

        // attention aggregate (attn aliases qbuf)
        agg_kernel<<<rowBlocks, 256, 0, stream>>>(qbuf, kvbuf, counts, eslot, qbuf, N);

        // hx = LN1(h + attn @ Wo + bo)  [fused GEMM+residual+LN] -> hbuf + hbf
        mfma_gemm<4, 8, 3, false, true, true><<<dim3(GX, 1), 256, 0, stream>>>(
            qbuf, wf + O_O + l * 16384, bo + l * 128, hbuf, hbuf, hbf,
            ln1w + l * 128, ln1b + l * 128, 128, 128, MTILES);

        // f1 = relu(hx @ Wf1 + bf1) -> bf16 [N,256]
        mfma_gemm<4, 8, 1, false, false, true><<<dim3(GX, 2), 256, 0, stream>>>(
            hbf, wf + F1_O + l * 32768, bf1 + l * 256, nullptr, nullptr, fbuf,
            nullptr, nullptr, 128, 256, MTILES);
        // h = hx + f1 @ Wf2 + bf2 (fp32, in-place residual)
        mfma_gemm<8, 4, 2, false, true, false><<<dim3(GX, 2), 256, 0, stream>>>(
            fbuf, wf + F2_O + l * 32768, bf2 + l * 128, hbuf, hbuf, nullptr,
            nullptr, nullptr, 256, 128, MTILES);

        // LN2 -> hbuf+hbf (layer 0) or d_out fp32 (layer 1)
        if (l == 0)
            ln_kernel<<<rowBlocks, 256, 0, stream>>>(hbuf, ln2w, ln2b, hbuf, hbf, N);
        else
            ln_kernel<<<rowBlocks, 256, 0, stream>>>(hbuf, ln2w + 128, ln2b + 128, out, nullptr, N);
    }
}

// Round 6
// 430.656 us; speedup vs baseline: 1.0176x; 1.0176x over previous
//
#include <hip/hip_runtime.h>
#include <math.h>

static constexpr int N_NODES = 50000;
static constexpr int N_EDGES = 800000;
static constexpr int DMODEL  = 128;
static constexpr int MTILES  = N_NODES / 16;   // 3125 exactly
static constexpr int CAPLOG  = 6;              // 64 slots/node; max degree ~40 (Poisson(16))
static constexpr int ESPLIT  = 400384;         // 391 blocks * 1024 edges

typedef __attribute__((ext_vector_type(8))) short short8;   // 8 bf16 (4 VGPRs)
typedef __attribute__((ext_vector_type(4))) float float4v;  // 4 fp32 acc

__device__ __forceinline__ unsigned short f2bf(float f) {
    unsigned u = __builtin_bit_cast(unsigned, f);
    u += 0x7fffu + ((u >> 16) & 1u);
    return (unsigned short)(u >> 16);
}
__device__ __forceinline__ float bf2f(unsigned short b) {
    unsigned u = ((unsigned)b) << 16;
    return __builtin_bit_cast(float, u);
}

// ---------------------------------------------------------------------------
// Weight prep: fp32 [K][N] row-major -> bf16 MFMA B-fragment order.
//   idx = (nt*ksteps + s)*512 + quad*128 + c*8 + j   (nt=n>>4, c=n&15, s=k>>5)
// ---------------------------------------------------------------------------
struct PrepSeg { const float* src; int K; int N; int dstOff; };
struct PrepArgs { PrepSeg seg[13]; };

__global__ void prep_kernel(PrepArgs pa, unsigned short* wf)
{
    PrepSeg sg = pa.seg[blockIdx.y];
    int e = blockIdx.x * 256 + threadIdx.x;
    int total = sg.K * sg.N;
    if (e >= total) return;
    int n = e % sg.N;
    int k = e / sg.N;
    int ks = sg.K >> 5;
    int nt = n >> 4, c = n & 15, s = k >> 5, q = (k >> 3) & 3, jj = k & 7;
    int di = sg.dstOff + (nt * ks + s) * 512 + q * 128 + c * 8 + jj;
    wf[di] = f2bf(sg.src[e]);
}

// ---------------------------------------------------------------------------
// Padded one-pass bucket build body: rank = atomicAdd(counts[dst]), slot into
// eslot[dst*64 + rank]. Fused into GEMM dispatches (extra blockIdx.y
// partition) so the atomic latency hides under MFMA/BW-bound work.
// ---------------------------------------------------------------------------
__device__ __forceinline__ void scatter_body(
    const int* __restrict__ src, const int* __restrict__ dst,
    int* counts, int* eslot, int ebeg, int eend)
{
    int base = ebeg + blockIdx.x * 1024 + threadIdx.x;
    int d[4], s[4];
    bool v[4];
#pragma unroll
    for (int k = 0; k < 4; ++k) {
        int e = base + k * 256;
        v[k] = e < eend;
        int ec = v[k] ? e : ebeg;
        d[k] = dst[ec];
        s[k] = src[ec];
    }
#pragma unroll
    for (int k = 0; k < 4; ++k) {
        if (v[k]) {
            int r = atomicAdd(&counts[d[k]], 1);
            eslot[(d[k] << CAPLOG) + r] = s[k];
        }
    }
}

// ---------------------------------------------------------------------------
// LDS-free MFMA GEMM body, 2-deep m-tile software pipeline: tile t+1's A
// loads are issued before tile t's MFMA/epilogue (these dispatches are
// memory-LATENCY-bound at 2 waves/SIMD: nothing else overlaps the A fetch).
// Wave = 16-row m-tile x NT*16 cols; B-frags in VGPRs (loaded once).
// EPI: 0=bias, 1=bias+relu, 2=bias+residual, 3=bias+residual+LayerNorm
// (EPI 3 requires NT*16==128, colBase==0).
// ---------------------------------------------------------------------------
template<int KSTEPS, int NT, int EPI, bool AF32, bool WRF, bool WRB>
__device__ __forceinline__ void gemm_body(
    const void* __restrict__ Ap, const unsigned short* __restrict__ Wfc,
    const float* __restrict__ bias, const float* res,
    float* Cf, unsigned short* Cb,
    const float* __restrict__ lnw, const float* __restrict__ lnb,
    int ldA, int ldC, int mtiles, int colBase)
{
    const int lane = threadIdx.x & 63;
    const int c = lane & 15;
    const int q = lane >> 4;

    short8 bfrag[NT][KSTEPS];
#pragma unroll
    for (int nt = 0; nt < NT; ++nt)
#pragma unroll
        for (int s = 0; s < KSTEPS; ++s)
            bfrag[nt][s] = *(const short8*)(Wfc + (nt * KSTEPS + s) * 512 + lane * 8);

    float bb[NT];
#pragma unroll
    for (int nt = 0; nt < NT; ++nt)
        bb[nt] = bias ? bias[colBase + nt * 16 + c] : 0.f;

    float lw[NT], lb[NT];
    if (EPI == 3) {
#pragma unroll
        for (int nt = 0; nt < NT; ++nt) {
            lw[nt] = lnw[nt * 16 + c];
            lb[nt] = lnb[nt * 16 + c];
        }
    }

    const int wid = blockIdx.x * 4 + (threadIdx.x >> 6);
    const int nw  = gridDim.x * 4;

    auto loadA = [&](int mt, short8* af) {
        const int row0 = mt * 16;
        if (AF32) {
            const float* A32 = (const float*)Ap;
#pragma unroll
            for (int s = 0; s < KSTEPS; ++s) {
                const float4* p = (const float4*)(A32 + (size_t)(row0 + c) * ldA + s * 32 + q * 8);
                float4 x0 = p[0], x1 = p[1];
                short8 a;
                a[0] = (short)f2bf(x0.x); a[1] = (short)f2bf(x0.y);
                a[2] = (short)f2bf(x0.z); a[3] = (short)f2bf(x0.w);
                a[4] = (short)f2bf(x1.x); a[5] = (short)f2bf(x1.y);
                a[6] = (short)f2bf(x1.z); a[7] = (short)f2bf(x1.w);
                af[s] = a;
            }
        } else {
            const unsigned short* Ab = (const unsigned short*)Ap;
#pragma unroll
            for (int s = 0; s < KSTEPS; ++s)
                af[s] = *(const short8*)(Ab + (size_t)(row0 + c) * ldA + s * 32 + q * 8);
        }
    };

    short8 aCur[KSTEPS], aNxt[KSTEPS];
    if (wid < mtiles) loadA(wid, aCur);

    for (int mt = wid; mt < mtiles; mt += nw) {
        const int row0 = mt * 16;
        const int mtn = mt + nw;
        if (mtn < mtiles) loadA(mtn, aNxt);   // prefetch next tile's A

        float4v acc[NT];
#pragma unroll
        for (int nt = 0; nt < NT; ++nt) acc[nt] = (float4v)0.f;
#pragma unroll
        for (int s = 0; s < KSTEPS; ++s)
#pragma unroll
            for (int nt = 0; nt < NT; ++nt)
                acc[nt] = __builtin_amdgcn_mfma_f32_16x16x32_bf16(aCur[s], bfrag[nt][s], acc[nt], 0, 0, 0);

        // epilogue: C row = row0 + q*4 + r, col = colBase + nt*16 + c
#pragma unroll
        for (int nt = 0; nt < NT; ++nt) {
            const int col = colBase + nt * 16 + c;
#pragma unroll
            for (int r = 0; r < 4; ++r) {
                const int grow = row0 + q * 4 + r;
                float v = acc[nt][r] + bb[nt];
                if (EPI == 2 || EPI == 3) v += res[(size_t)grow * ldC + col];
                if (EPI == 1) v = fmaxf(v, 0.f);
                acc[nt][r] = v;
            }
        }

        if (EPI == 3) {
            // full-row LayerNorm: reduce over 16 lanes of quad (cols) x NT regs
#pragma unroll
            for (int r = 0; r < 4; ++r) {
                float s = 0.f, ss = 0.f;
#pragma unroll
                for (int nt = 0; nt < NT; ++nt) {
                    float v = acc[nt][r];
                    s += v; ss = fmaf(v, v, ss);
                }
#pragma unroll
                for (int o = 1; o < 16; o <<= 1) {
                    s  += __shfl_xor(s, o, 64);
                    ss += __shfl_xor(ss, o, 64);
                }
                float m   = s * (1.0f / 128.0f);
                float var = ss * (1.0f / 128.0f) - m * m;
                float rs  = rsqrtf(var + 1e-5f);
                const int grow = row0 + q * 4 + r;
#pragma unroll
                for (int nt = 0; nt < NT; ++nt) {
                    float v = (acc[nt][r] - m) * rs * lw[nt] + lb[nt];
                    if (WRF) Cf[(size_t)grow * ldC + nt * 16 + c] = v;
                    if (WRB) Cb[(size_t)grow * ldC + nt * 16 + c] = f2bf(v);
                }
            }
        } else {
#pragma unroll
            for (int nt = 0; nt < NT; ++nt) {
                const int col = colBase + nt * 16 + c;
#pragma unroll
                for (int r = 0; r < 4; ++r) {
                    const int grow = row0 + q * 4 + r;
                    if (WRF) Cf[(size_t)grow * ldC + col] = acc[nt][r];
                    if (WRB) Cb[(size_t)grow * ldC + col] = f2bf(acc[nt][r]);
                }
            }
        }

#pragma unroll
        for (int s = 0; s < KSTEPS; ++s) aCur[s] = aNxt[s];
    }
}

template<int KSTEPS, int NT, int EPI, bool AF32, bool WRF, bool WRB>
__global__ __launch_bounds__(256, 2)
void mfma_gemm(const void* __restrict__ Ap, const unsigned short* __restrict__ Wf,
               const float* __restrict__ bias, const float* res,
               float* Cf, unsigned short* Cb,
               const float* __restrict__ lnw, const float* __restrict__ lnb,
               int ldA, int ldC, int mtiles)
{
    const int colBase = blockIdx.y * NT * 16;
    const unsigned short* Wfc = Wf + (size_t)blockIdx.y * NT * KSTEPS * 512;
    gemm_body<KSTEPS, NT, EPI, AF32, WRF, WRB>(
        Ap, Wfc, bias, res, Cf, Cb, lnw, lnb, ldA, ldC, mtiles, colBase);
}

// Embedding GEMM fused with scatter half 1 (blockIdx.y==1 -> scatter).
__global__ __launch_bounds__(256, 2)
void emb_sc_gemm(const float* __restrict__ A, const unsigned short* __restrict__ Wf,
                 float* Cf, unsigned short* Cb, int mtiles,
                 const int* __restrict__ src, const int* __restrict__ dst,
                 int* counts, int* eslot, int ebeg, int eend)
{
    if (blockIdx.y == 1) {
        scatter_body(src, dst, counts, eslot, ebeg, eend);
        return;
    }
    gemm_body<4, 8, 0, true, true, true>(
        A, Wf, nullptr, nullptr, Cf, Cb, nullptr, nullptr, 128, 128, mtiles, 0);
}

// Q/K/V fused + scatter half 2 (blockIdx.y==3 -> scatter on layer 0).
// K and V write into the interleaved kv buffer [node][K 0..127 | V 128..255]
// via per-sel out pointer + ldC.
struct QkvPtrs { const float* bias[3]; unsigned short* out[3]; int ldc[3]; };

__global__ __launch_bounds__(256, 2)
void qkv_sc_gemm(const unsigned short* __restrict__ A, const unsigned short* __restrict__ WfBase,
                 QkvPtrs ptrs, int mtiles,
                 const int* __restrict__ src, const int* __restrict__ dst,
                 int* counts, int* eslot, int ebeg, int eend)
{
    if (blockIdx.y == 3) {
        scatter_body(src, dst, counts, eslot, ebeg, eend);
        return;
    }
    const int sel = blockIdx.y;
    gemm_body<4, 8, 0, false, false, true>(
        A, WfBase + (size_t)sel * 32768, ptrs.bias[sel], nullptr,
        nullptr, ptrs.out[sel], nullptr, nullptr, 128, ptrs.ldc[sel], mtiles, 0);
}

// ---------------------------------------------------------------------------
// LayerNorm rows of [M,128] fp32; writes fp32 (+optional bf16 mirror).
// ---------------------------------------------------------------------------
__global__ __launch_bounds__(256)
void ln_kernel(const float* x, const float* __restrict__ w,
               const float* __restrict__ b, float* outf, unsigned short* outb, int M)
{
    int row  = (int)((blockIdx.x * 256 + threadIdx.x) >> 6);
    int lane = threadIdx.x & 63;
    if (row >= M) return;
    const float* xr = x + (size_t)row * 128;
    float x0 = xr[lane];
    float x1 = xr[lane + 64];
    float s  = x0 + x1;
    float ss = x0 * x0 + x1 * x1;
#pragma unroll
    for (int o = 1; o < 64; o <<= 1) {
        s  += __shfl_xor(s, o, 64);
        ss += __shfl_xor(ss, o, 64);
    }
    float m   = s * (1.0f / 128.0f);
    float var = ss * (1.0f / 128.0f) - m * m;
    float rs  = rsqrtf(var + 1e-5f);
    float o0 = (x0 - m) * rs * w[lane] + b[lane];
    float o1 = (x1 - m) * rs * w[lane + 64] + b[lane + 64];
    outf[(size_t)row * 128 + lane]      = o0;
    outf[(size_t)row * 128 + lane + 64] = o1;
    if (outb) {
        outb[(size_t)row * 128 + lane]      = f2bf(o0);
        outb[(size_t)row * 128 + lane + 64] = f2bf(o1);
    }
}

// ---------------------------------------------------------------------------
// Attention aggregation (R4 form — measured best: 55.7us, VGPR 32, occ 67%).
// 16-lanes-per-edge, 8 edges/iter. TLP at ~8 waves/SIMD hides gather latency;
// deeper per-wave unroll/prefetch measured WORSE (R2: 16-edge, R5: dbuf).
//   wave = one dst node; quarter g=lane>>4 owns edge slots g and g+4; lane
//   li=lane&15 covers dims 8*li..8*li+7 (head = li>>1). K|V interleaved rows:
//   each edge reads one contiguous 512B region (K at +0, V at +128 elems).
//   Head score = 1 xor-1 shuffle. Final cross-quarter combine: xor-16/32.
//   Buckets padded: beg = w<<6, end = beg + counts[w].
//   attn may alias q (row w read at start / written at end by wave w only).
// ---------------------------------------------------------------------------
__global__ __launch_bounds__(256)
void agg_kernel(const unsigned short* qv, const unsigned short* __restrict__ kvv,
                const int* __restrict__ counts, const int* __restrict__ eslot,
                unsigned short* attn, int n_nodes)
{
    int w    = (int)((blockIdx.x * 256 + threadIdx.x) >> 6);
    int lane = threadIdx.x & 63;
    if (w >= n_nodes) return;
    const int g  = lane >> 4;   // edge slot within iteration
    const int li = lane & 15;   // 8-dim chunk; head = li>>1

    // q chunk: dims 8*li .. 8*li+7 (quarters redundantly load same 256B row -> L1)
    float qf[8];
    {
        uint4 qb = *(const uint4*)(qv + (size_t)w * 128 + li * 8);
        const unsigned* qp = (const unsigned*)&qb;
#pragma unroll
        for (int j = 0; j < 4; ++j) {
            qf[2 * j]     = bf2f((unsigned short)(qp[j] & 0xffff));
            qf[2 * j + 1] = bf2f((unsigned short)(qp[j] >> 16));
        }
    }

    const int beg = w << CAPLOG;
    const int end = beg + counts[w];
    float acc[8] = {0.f, 0.f, 0.f, 0.f, 0.f, 0.f, 0.f, 0.f};
    float z = 0.f;

    for (int e = beg; e < end; e += 8) {
        int  i0 = e + g;
        int  i1 = e + g + 4;
        bool v0 = i0 < end;
        bool v1 = i1 < end;
        int  s0 = eslot[v0 ? i0 : beg];
        int  s1 = eslot[v1 ? i1 : beg];

        const unsigned short* b0 = kvv + (size_t)s0 * 256 + li * 8;
        const unsigned short* b1 = kvv + (size_t)s1 * 256 + li * 8;
        uint4 kb0 = *(const uint4*)(b0);
        uint4 vb0 = *(const uint4*)(b0 + 128);
        uint4 kb1 = *(const uint4*)(b1);
        uint4 vb1 = *(const uint4*)(b1 + 128);

        const unsigned* kp0 = (const unsigned*)&kb0;
        const unsigned* kp1 = (const unsigned*)&kb1;
        float p0 = 0.f, p1 = 0.f;
#pragma unroll
        for (int j = 0; j < 4; ++j) {
            p0 = fmaf(bf2f((unsigned short)(kp0[j] & 0xffff)), qf[2 * j],     p0);
            p0 = fmaf(bf2f((unsigned short)(kp0[j] >> 16)),    qf[2 * j + 1], p0);
            p1 = fmaf(bf2f((unsigned short)(kp1[j] & 0xffff)), qf[2 * j],     p1);
            p1 = fmaf(bf2f((unsigned short)(kp1[j] >> 16)),    qf[2 * j + 1], p1);
        }
        p0 += __shfl_xor(p0, 1, 64);   // full 16-dim head score
        p1 += __shfl_xor(p1, 1, 64);

        float sv0 = __expf(fminf(fmaxf(p0 * 0.25f, -5.f), 5.f));
        float sv1 = __expf(fminf(fmaxf(p1 * 0.25f, -5.f), 5.f));
        sv0 = v0 ? sv0 : 0.f;
        sv1 = v1 ? sv1 : 0.f;

        const unsigned* vp0 = (const unsigned*)&vb0;
        const unsigned* vp1 = (const unsigned*)&vb1;
#pragma unroll
        for (int j = 0; j < 4; ++j) {
            acc[2 * j]     = fmaf(sv0, bf2f((unsigned short)(vp0[j] & 0xffff)), acc[2 * j]);
            acc[2 * j + 1] = fmaf(sv0, bf2f((unsigned short)(vp0[j] >> 16)),    acc[2 * j + 1]);
            acc[2 * j]     = fmaf(sv1, bf2f((unsigned short)(vp1[j] & 0xffff)), acc[2 * j]);
            acc[2 * j + 1] = fmaf(sv1, bf2f((unsigned short)(vp1[j] >> 16)),    acc[2 * j + 1]);
        }
        z += sv0 + sv1;
    }

    // combine the 4 edge-slot quarters (each lane group holds same dims/head)
#pragma unroll
    for (int o = 16; o < 64; o <<= 1) {
#pragma unroll
        for (int j = 0; j < 8; ++j) acc[j] += __shfl_xor(acc[j], o, 64);
        z += __shfl_xor(z, o, 64);
    }

    if (g == 0) {
        float inv = 1.f / (z + 1e-6f);
        unsigned ow[4];
#pragma unroll
        for (int j = 0; j < 4; ++j)
            ow[j] = (unsigned)f2bf(acc[2 * j] * inv) |
                    ((unsigned)f2bf(acc[2 * j + 1] * inv) << 16);
        *(uint4*)(attn + (size_t)w * 128 + li * 8) = *(const uint4*)ow;
    }
}

// ---------------------------------------------------------------------------
extern "C" void kernel_launch(void* const* d_in, const int* in_sizes, int n_in,
                              void* d_out, int out_size, void* d_ws, size_t ws_size,
                              hipStream_t stream)
{
    const float* h_in  = (const float*)d_in[0];
    const int*   src   = (const int*)d_in[1];
    const int*   dst   = (const int*)d_in[2];
    const float* W_emb = (const float*)d_in[3];
    const float* Wq    = (const float*)d_in[4];
    const float* bq    = (const float*)d_in[5];
    const float* Wk    = (const float*)d_in[6];
    const float* bk    = (const float*)d_in[7];
    const float* Wv    = (const float*)d_in[8];
    const float* bv    = (const float*)d_in[9];
    const float* Wo    = (const float*)d_in[10];
    const float* bo    = (const float*)d_in[11];
    const float* ln1w  = (const float*)d_in[12];
    const float* ln1b  = (const float*)d_in[13];
    const float* Wf1   = (const float*)d_in[14];
    const float* bf1   = (const float*)d_in[15];
    const float* Wf2   = (const float*)d_in[16];
    const float* bf2   = (const float*)d_in[17];
    const float* ln2w  = (const float*)d_in[18];
    const float* ln2b  = (const float*)d_in[19];
    float* out = (float*)d_out;

    const int N = N_NODES, E = N_EDGES;
    const size_t NF = (size_t)N * DMODEL;

    float*          hbuf  = (float*)d_ws;
    unsigned short* hbf   = (unsigned short*)(hbuf + NF);
    unsigned short* qbuf  = hbf + NF;
    unsigned short* kvbuf = qbuf + NF;        // [N][256]: K row | V row interleaved
    unsigned short* wf    = kvbuf + 2 * NF;
    int* counts = (int*)(wf + 278528);
    // padded edge buckets live in d_out: dead until the final ln_kernel
    // (which completely overwrites it). 50K * 64 slots * 4B = 12.8 MB < 25.6 MB.
    int* eslot  = (int*)d_out;
    unsigned short* fbuf = kvbuf;   // [N][256] bf16 FFN hidden (same footprint)

    const int EMB_O = 0, Q_O = 16384, K_O = 49152, V_O = 81920, O_O = 114688,
              F1_O = 147456, F2_O = 212992;

    const int rowBlocks = (N + 3) / 4;
    const int GX = 391;

    // ---- counts zero (scatter halves are fused into emb/qkv dispatches) ----
    hipMemsetAsync(counts, 0, (size_t)N * sizeof(int), stream);

    // ---- weight prep ----
    PrepArgs pa;
    pa.seg[0]  = {W_emb,          128, 128, EMB_O};
    pa.seg[1]  = {Wq,             128, 128, Q_O};
    pa.seg[2]  = {Wq + 16384,     128, 128, Q_O + 16384};
    pa.seg[3]  = {Wk,             128, 128, K_O};
    pa.seg[4]  = {Wk + 16384,     128, 128, K_O + 16384};
    pa.seg[5]  = {Wv,             128, 128, V_O};
    pa.seg[6]  = {Wv + 16384,     128, 128, V_O + 16384};
    pa.seg[7]  = {Wo,             128, 128, O_O};
    pa.seg[8]  = {Wo + 16384,     128, 128, O_O + 16384};
    pa.seg[9]  = {Wf1,            128, 256, F1_O};
    pa.seg[10] = {Wf1 + 32768,    128, 256, F1_O + 32768};
    pa.seg[11] = {Wf2,            256, 128, F2_O};
    pa.seg[12] = {Wf2 + 32768,    256, 128, F2_O + 32768};
    prep_kernel<<<dim3(128, 13), 256, 0, stream>>>(pa, wf);

    // ---- embedding GEMM + scatter half 1 (edges [0, ESPLIT)) ----
    emb_sc_gemm<<<dim3(GX, 2), 256, 0, stream>>>(
        h_in, wf + EMB_O, hbuf, hbf, MTILES, src, dst, counts, eslot, 0, ESPLIT);

    for (int l = 0; l < 2; ++l) {
        // Q,K,V in one dispatch (+ scatter half 2 on layer 0)
        QkvPtrs qp;
        qp.bias[0] = bq + l * 128; qp.bias[1] = bk + l * 128; qp.bias[2] = bv + l * 128;
        qp.out[0] = qbuf;   qp.ldc[0] = 128;
        qp.out[1] = kvbuf;  qp.ldc[1] = 256;
        qp.out[2] = kvbuf + 128; qp.ldc[2] = 256;
        qkv_sc_gemm<<<dim3(GX, l == 0 ? 4 : 3), 256, 0, stream>>>(
            hbf, wf + Q_O + l * 16384, qp, MTILES, src, dst, counts, eslot, ESPLIT, E);

        // attention aggregate (attn aliases qbuf)
        agg_kernel<<<rowBlocks, 256, 0, stream>>>(qbuf, kvbuf, counts, eslot, qbuf, N);

        // hx = LN1(h + attn @ Wo + bo)  [fused GEMM+residual+LN] -> hbuf + hbf
        mfma_gemm<4, 8, 3, false, true, true><<<dim3(GX, 1), 256, 0, stream>>>(
            qbuf, wf + O_O + l * 16384, bo + l * 128, hbuf, hbuf, hbf,
            ln1w + l * 128, ln1b + l * 128, 128, 128, MTILES);

        // f1 = relu(hx @ Wf1 + bf1) -> bf16 [N,256]
        mfma_gemm<4, 8, 1, false, false, true><<<dim3(GX, 2), 256, 0, stream>>>(
            hbf, wf + F1_O + l * 32768, bf1 + l * 256, nullptr, nullptr, fbuf,
            nullptr, nullptr, 128, 256, MTILES);
        // h = hx + f1 @ Wf2 + bf2 (fp32, in-place residual)
        mfma_gemm<8, 4, 2, false, true, false><<<dim3(GX, 2), 256, 0, stream>>>(
            fbuf, wf + F2_O + l * 32768, bf2 + l * 128, hbuf, hbuf, nullptr,
            nullptr, nullptr, 256, 128, MTILES);

        // LN2 -> hbuf+hbf (layer 0) or d_out fp32 (layer 1)
        if (l == 0)
            ln_kernel<<<rowBlocks, 256, 0, stream>>>(hbuf, ln2w, ln2b, hbuf, hbf, N);
        else
            ln_kernel<<<rowBlocks, 256, 0, stream>>>(hbuf, ln2w + 128, ln2b + 128, out, nullptr, N);
    }
}